// Round 2
// baseline (1610.400 us; speedup 1.0000x reference)
//
#include <hip/hip_runtime.h>
#include <hip/hip_cooperative_groups.h>
#include <stdint.h>

namespace cg = cooperative_groups;

// SparseDecoder: 4-layer masked MLP forward.
//   x:[64,512] fp32; layer i: K=SIZES[i] -> N=SIZES[i+1]
//   z_i = x @ (W_i * mask_i)^T + b_i ; relu between layers (applied on READ
//   by the next layer's GEMM; each GEMM stores pre-activation z).
//
// ROUND 2 THEORY: round-1 reg-streaming version (6 dispatches) ran 1471 us
// (~1 TB/s on the 1.42 GB compulsory W+mask stream; harness fills prove
// 6.4 TB/s is reachable). Per-layer grids left 1/2..3/4 of SIMDs idle on
// layers 0-2 and the profiler's top-k hid every GEMM dispatch behind 330-us
// harness poison-fills. This round: ONE cooperative persistent kernel
// (probe + bias init + 4 layers with grid.sync between), grid sized from the
// occupancy API so all blocks are resident, per-layer K-splits chosen so
// wave-tiles >= resident waves. Inner loop unchanged: one wave = one
// 64n x 64batch tile, HBM -> VGPR -> bf16 MFMA, atomicAdd K-split partials
// into bias-initialized z buffers. Fallback to the round-1 separate-kernel
// path if cooperative launch is unavailable.
//
// MASK DTYPE: runtime probe detects int32 vs u8 bool layout (per-block,
// no cross-block communication needed).

typedef short bf16x8 __attribute__((ext_vector_type(8)));   // 8 bf16 (4 VGPRs)
typedef float f32x4  __attribute__((ext_vector_type(4)));   // 4 fp32 acc

__device__ __forceinline__ unsigned short f2bf(float f) {
    // round-to-nearest-even fp32 -> bf16 (finite inputs)
    unsigned int u = __float_as_uint(f);
    return (unsigned short)((u + 0x7FFFu + ((u >> 16) & 1u)) >> 16);
}

__device__ __forceinline__ unsigned int bfpair(float lo, float hi) {
    return (unsigned int)f2bf(lo) | ((unsigned int)f2bf(hi) << 16);
}

__device__ __forceinline__ bf16x8 pack8(const float4& a, const float4& b) {
    union { unsigned int u[4]; bf16x8 v; } r;
    r.u[0] = bfpair(a.x, a.y);
    r.u[1] = bfpair(a.z, a.w);
    r.u[2] = bfpair(b.x, b.y);
    r.u[3] = bfpair(b.z, b.w);
    return r.v;
}

// Inner streaming loop. MU8: mask dtype (1 = u8 bools, 0 = int32).
// RELU: apply relu to x on read (layers 1..3).
// Per 32-wide k-step, lane (lr,quad):
//   A-frag[ng]: W[n0+ng*16+lr][k+quad*8 .. +8]  (2x float4 + mask, select, cvt)
//   B-frag[bg]: x[bg*16+lr]  [k+quad*8 .. +8]  (2x float4, relu, cvt)
//   16 MFMA (4 ng x 4 bg) accumulate the 64x64 tile.
template <int MU8, int RELU>
__device__ __forceinline__ void gemm_loop(
    const float* __restrict__ X, const float* __restrict__ W,
    const unsigned char* __restrict__ Mk,
    int K, int kbeg, int kend, int n0, int lr, int quad, f32x4 (&acc)[4][4])
{
    const int* __restrict__ Mk32 = (const int*)Mk;
    const size_t xoff = (size_t)lr * K + quad * 8;            // + bg*16*K + k
    const size_t woff = (size_t)(n0 + lr) * K + quad * 8;     // + ng*16*K + k

    #pragma unroll 1
    for (int k = kbeg; k < kend; k += 32) {
        // ---- B fragments: all 64 batches, this wave only ----
        bf16x8 bfr[4];
        #pragma unroll
        for (int bg = 0; bg < 4; ++bg) {
            const float* xp = X + xoff + (size_t)bg * 16 * K + k;
            float4 x0 = *(const float4*)xp;
            float4 x1 = *(const float4*)(xp + 4);
            if (RELU) {
                x0.x = fmaxf(x0.x, 0.f); x0.y = fmaxf(x0.y, 0.f);
                x0.z = fmaxf(x0.z, 0.f); x0.w = fmaxf(x0.w, 0.f);
                x1.x = fmaxf(x1.x, 0.f); x1.y = fmaxf(x1.y, 0.f);
                x1.z = fmaxf(x1.z, 0.f); x1.w = fmaxf(x1.w, 0.f);
            }
            bfr[bg] = pack8(x0, x1);
        }
        // ---- A fragments (masked W) + MFMA ----
        #pragma unroll
        for (int ng = 0; ng < 4; ++ng) {
            size_t e = woff + (size_t)ng * 16 * K + k;
            float4 w0 = *(const float4*)(W + e);
            float4 w1 = *(const float4*)(W + e + 4);
            if (MU8) {
                uint2 m8 = *(const uint2*)(Mk + e);   // 8 mask bytes
                w0.x = (m8.x & 0x000000FFu) ? w0.x : 0.f;
                w0.y = (m8.x & 0x0000FF00u) ? w0.y : 0.f;
                w0.z = (m8.x & 0x00FF0000u) ? w0.z : 0.f;
                w0.w = (m8.x & 0xFF000000u) ? w0.w : 0.f;
                w1.x = (m8.y & 0x000000FFu) ? w1.x : 0.f;
                w1.y = (m8.y & 0x0000FF00u) ? w1.y : 0.f;
                w1.z = (m8.y & 0x00FF0000u) ? w1.z : 0.f;
                w1.w = (m8.y & 0xFF000000u) ? w1.w : 0.f;
            } else {
                int4 mm0 = *(const int4*)(Mk32 + e);
                int4 mm1 = *(const int4*)(Mk32 + e + 4);
                w0.x = mm0.x ? w0.x : 0.f;
                w0.y = mm0.y ? w0.y : 0.f;
                w0.z = mm0.z ? w0.z : 0.f;
                w0.w = mm0.w ? w0.w : 0.f;
                w1.x = mm1.x ? w1.x : 0.f;
                w1.y = mm1.y ? w1.y : 0.f;
                w1.z = mm1.z ? w1.z : 0.f;
                w1.w = mm1.w ? w1.w : 0.f;
            }
            bf16x8 a = pack8(w0, w1);
            #pragma unroll
            for (int bg = 0; bg < 4; ++bg)
                acc[ng][bg] = __builtin_amdgcn_mfma_f32_16x16x32_bf16(
                    a, bfr[bg], acc[ng][bg], 0, 0, 0);
        }
    }
}

// One wave computes one 64n x 64batch tile over K-range [kbeg, kend).
template <int MU8, int RELU>
__device__ __forceinline__ void gemm_tile(
    const float* __restrict__ X, const float* __restrict__ W,
    const unsigned char* __restrict__ Mk,
    float* __restrict__ Z, int N, int K,
    int kbeg, int kend, int n0, int lr, int quad)
{
    f32x4 acc[4][4];
    #pragma unroll
    for (int i = 0; i < 4; ++i)
        #pragma unroll
        for (int j = 0; j < 4; ++j) acc[i][j] = (f32x4){0.f, 0.f, 0.f, 0.f};

    gemm_loop<MU8, RELU>(X, W, Mk, K, kbeg, kend, n0, lr, quad, acc);

    // --- epilogue: D layout col=lane&15 (batch), row=quad*4+reg (n) ---
    #pragma unroll
    for (int ng = 0; ng < 4; ++ng) {
        #pragma unroll
        for (int bg = 0; bg < 4; ++bg) {
            int b = bg * 16 + lr;
            float* zp = Z + (size_t)b * N + n0 + ng * 16 + quad * 4;
            #pragma unroll
            for (int r = 0; r < 4; ++r) atomicAdd(&zp[r], acc[ng][bg][r]);
        }
    }
}

template <int RELU>
__device__ __forceinline__ void run_layer(
    const float* __restrict__ X, const float* __restrict__ W,
    const unsigned char* __restrict__ Mk, int mu8,
    float* __restrict__ Z, int N, int K, int nk,
    int wid, int nw, int lr, int quad)
{
    const int ntx    = N >> 6;           // power of 2 (32/64/128/256)
    const int sh     = 31 - __clz(ntx);
    const int kper   = K / nk;
    const int ntiles = ntx * nk;
    for (int t = wid; t < ntiles; t += nw) {
        int n0   = (t & (ntx - 1)) << 6;
        int kbeg = (t >> sh) * kper;
        if (mu8) gemm_tile<1, RELU>(X, W, Mk, Z, N, K, kbeg, kbeg + kper, n0, lr, quad);
        else     gemm_tile<0, RELU>(X, W, Mk, Z, N, K, kbeg, kbeg + kper, n0, lr, quad);
    }
}

// Fused persistent kernel: mask probe + bias init + 4 layers, grid.sync
// between layers. 256 threads = 4 independent waves; each wave grid-strides
// over that layer's (n-tile, k-split) work items.
__global__ __launch_bounds__(256, 2) void fused_mlp(
    const float* __restrict__ x,
    const float* __restrict__ W0, const float* __restrict__ b0, const unsigned char* __restrict__ m0,
    const float* __restrict__ W1, const float* __restrict__ b1, const unsigned char* __restrict__ m1,
    const float* __restrict__ W2, const float* __restrict__ b2, const unsigned char* __restrict__ m2,
    const float* __restrict__ W3, const float* __restrict__ b3, const unsigned char* __restrict__ m3,
    float* __restrict__ z0, float* __restrict__ z1,
    float* __restrict__ z2, float* __restrict__ z3,
    int nk0, int nk1, int nk2, int nk3)
{
    cg::grid_group grid = cg::this_grid();

    // ---- mask-kind probe, per block (every block scans the same 16 KB of
    // mask0; L2-resident, no cross-block communication). int32 bools have
    // all upper 3 bytes zero; u8 bools don't. ----
    __shared__ int s_any;
    if (threadIdx.x == 0) s_any = 0;
    __syncthreads();
    {
        const unsigned int* mm = (const unsigned int*)m0;
        int any = 0;
        #pragma unroll
        for (int it = 0; it < 16; ++it) {
            unsigned int v = mm[it * 256 + threadIdx.x];
            if (v & 0xFFFFFF00u) any = 1;
        }
        if (__any(any) && (threadIdx.x & 63) == 0) s_any = 1;
    }
    __syncthreads();
    const int mu8 = s_any;   // 1 => u8 bools, 0 => int32

    // ---- bias init: z_i[b][n] = b_i[n], grid-stride (all sizes pow2) ----
    {
        const unsigned tr = blockIdx.x * 256u + threadIdx.x;
        const unsigned tn = gridDim.x * 256u;
        for (unsigned i = tr; i < 64u * 2048u;  i += tn) z0[i] = b0[i & 2047u];
        for (unsigned i = tr; i < 64u * 4096u;  i += tn) z1[i] = b1[i & 4095u];
        for (unsigned i = tr; i < 64u * 8192u;  i += tn) z2[i] = b2[i & 8191u];
        for (unsigned i = tr; i < 64u * 16384u; i += tn) z3[i] = b3[i & 16383u];
    }

    grid.sync();

    const int wid  = (blockIdx.x << 2) | (threadIdx.x >> 6);
    const int nw   = gridDim.x << 2;
    const int l    = threadIdx.x & 63;
    const int lr   = l & 15;
    const int quad = l >> 4;

    run_layer<0>(x,  W0, m0, mu8, z0, 2048,  512,  nk0, wid, nw, lr, quad);
    grid.sync();
    run_layer<1>(z0, W1, m1, mu8, z1, 4096,  2048, nk1, wid, nw, lr, quad);
    grid.sync();
    run_layer<1>(z1, W2, m2, mu8, z2, 8192,  4096, nk2, wid, nw, lr, quad);
    grid.sync();
    run_layer<1>(z2, W3, m3, mu8, z3, 16384, 8192, nk3, wid, nw, lr, quad);
}

// ---------------- fallback path (round-1 kernels) ----------------

__global__ __launch_bounds__(256) void probe_mask_kind(
    const unsigned int* __restrict__ m, int* __restrict__ flag)
{
    __shared__ int s_any;
    if (threadIdx.x == 0) s_any = 0;
    __syncthreads();
    int any = 0;
    #pragma unroll
    for (int it = 0; it < 16; ++it) {
        unsigned int v = m[it * 256 + threadIdx.x];
        if (v & 0xFFFFFF00u) any = 1;
    }
    if (__any(any) && (threadIdx.x & 63) == 0) s_any = 1;
    __syncthreads();
    if (threadIdx.x == 0) flag[0] = s_any;
}

__global__ __launch_bounds__(256) void init_bias_all(
    const float* __restrict__ b0, const float* __restrict__ b1,
    const float* __restrict__ b2, const float* __restrict__ b3,
    float* __restrict__ z0, float* __restrict__ z1,
    float* __restrict__ z2, float* __restrict__ z3)
{
    int n = blockIdx.x * 256 + threadIdx.x;
    int b = blockIdx.y;
    if (n < 2048)             z0[(size_t)b * 2048  + n]           = b0[n];
    else if (n < 6144)        z1[(size_t)b * 4096  + (n - 2048)]  = b1[n - 2048];
    else if (n < 14336)       z2[(size_t)b * 8192  + (n - 6144)]  = b2[n - 6144];
    else                      z3[(size_t)b * 16384 + (n - 14336)] = b3[n - 14336];
}

__global__ __launch_bounds__(64, 2) void sparse_gemm_rf(
    const float* __restrict__ X, const float* __restrict__ W,
    const unsigned char* __restrict__ Mk, const int* __restrict__ mflag,
    float* __restrict__ Z, int N, int K, int kper, int relu_in)
{
    const int l    = threadIdx.x;
    const int lr   = l & 15;
    const int quad = l >> 4;
    const int n0   = blockIdx.x * 64;
    const int kbeg = blockIdx.y * kper;
    const int mu8  = *mflag;

    if (mu8) {
        if (relu_in) gemm_tile<1, 1>(X, W, Mk, Z, N, K, kbeg, kbeg + kper, n0, lr, quad);
        else         gemm_tile<1, 0>(X, W, Mk, Z, N, K, kbeg, kbeg + kper, n0, lr, quad);
    } else {
        if (relu_in) gemm_tile<0, 1>(X, W, Mk, Z, N, K, kbeg, kbeg + kper, n0, lr, quad);
        else         gemm_tile<0, 0>(X, W, Mk, Z, N, K, kbeg, kbeg + kper, n0, lr, quad);
    }
}

extern "C" void kernel_launch(void* const* d_in, const int* in_sizes, int n_in,
                              void* d_out, int out_size, void* d_ws, size_t ws_size,
                              hipStream_t stream) {
    // setup_inputs order: x, W0,b0,mask0, W1,b1,mask1, W2,b2,mask2, W3,b3,mask3
    const float* x  = (const float*)d_in[0];
    const float* W0 = (const float*)d_in[1];
    const float* b0 = (const float*)d_in[2];
    const unsigned char* m0 = (const unsigned char*)d_in[3];
    const float* W1 = (const float*)d_in[4];
    const float* b1 = (const float*)d_in[5];
    const unsigned char* m1 = (const unsigned char*)d_in[6];
    const float* W2 = (const float*)d_in[7];
    const float* b2 = (const float*)d_in[8];
    const unsigned char* m2 = (const unsigned char*)d_in[9];
    const float* W3 = (const float*)d_in[10];
    const float* b3 = (const float*)d_in[11];
    const unsigned char* m3 = (const unsigned char*)d_in[12];

    float* z0 = (float*)d_ws;              // [64, 2048]
    float* z1 = z0 + (size_t)64 * 2048;    // [64, 4096]
    float* z2 = z1 + (size_t)64 * 4096;    // [64, 8192]
    float* z3 = (float*)d_out;             // [64, 16384]

    // Grid: all blocks resident (cooperative requirement). Query once.
    static int blocksPerCU = -1;
    if (blocksPerCU < 0) {
        hipError_t e = hipOccupancyMaxActiveBlocksPerMultiprocessor(
            &blocksPerCU, reinterpret_cast<const void*>(&fused_mlp), 256, 0);
        if (e != hipSuccess || blocksPerCU <= 0) blocksPerCU = 2;
        if (blocksPerCU > 8) blocksPerCU = 8;
    }
    int G = blocksPerCU * 256;
    if (G > 2048) G = 2048;
    const int WV = G * 4;   // resident waves

    // Per-layer K-split count: smallest pow2 with ntx*nk >= WV, kper >= 64.
    auto pick_nk = [&](int ntx, int K) {
        int nk = 1;
        while (ntx * nk < WV && (K / (nk * 2)) >= 64) nk <<= 1;
        return nk;
    };
    int nk0 = pick_nk(32,  512);
    int nk1 = pick_nk(64,  2048);
    int nk2 = pick_nk(128, 4096);
    int nk3 = pick_nk(256, 8192);

    void* args[] = {
        (void*)&x,
        (void*)&W0, (void*)&b0, (void*)&m0,
        (void*)&W1, (void*)&b1, (void*)&m1,
        (void*)&W2, (void*)&b2, (void*)&m2,
        (void*)&W3, (void*)&b3, (void*)&m3,
        (void*)&z0, (void*)&z1, (void*)&z2, (void*)&z3,
        (void*)&nk0, (void*)&nk1, (void*)&nk2, (void*)&nk3
    };
    hipError_t le = hipLaunchCooperativeKernel(
        reinterpret_cast<const void*>(&fused_mlp),
        dim3(G), dim3(256), args, 0, stream);

    if (le != hipSuccess) {
        // Fallback: round-1 separate-kernel path.
        int* mflag = (int*)(z2 + (size_t)64 * 8192);
        probe_mask_kind<<<1, 256, 0, stream>>>((const unsigned int*)m0, mflag);
        init_bias_all<<<dim3(120, 64), 256, 0, stream>>>(b0, b1, b2, b3, z0, z1, z2, z3);
        sparse_gemm_rf<<<dim3(32, 8),  64, 0, stream>>>(x,  W0, m0, mflag, z0, 2048,  512,   64, 0);
        sparse_gemm_rf<<<dim3(64, 8),  64, 0, stream>>>(z0, W1, m1, mflag, z1, 4096,  2048, 256, 1);
        sparse_gemm_rf<<<dim3(128, 8), 64, 0, stream>>>(z1, W2, m2, mflag, z2, 8192,  4096, 512, 1);
        sparse_gemm_rf<<<dim3(256, 8), 64, 0, stream>>>(z2, W3, m3, mflag, z3, 16384, 8192, 1024, 1);
    }
}